// Round 7
// baseline (126.327 us; speedup 1.0000x reference)
//
#include <hip/hip_runtime.h>
#include <hip/hip_bf16.h>

#define Bsz 256
#define Tn 2048
#define QD 1024
#define AD 128
#define DCn 8
#define DKn 21
#define PLn 11
#define GN (DCn * DKn)   // 168
#define XS2 24           // X row stride in halfs (48 B; rows 16B-aligned)
#define SEGT 256         // t's per main block
#define NSEG (Tn / SEGT) // 8

typedef _Float16 f16x8 __attribute__((ext_vector_type(8)));
typedef float f32x4 __attribute__((ext_vector_type(4)));

#define TWO_LOG2E 2.8853900817779268f   // 2*log2(e): folds tanh's 2x and exp->exp2

// ---------------------------------------------------------------------------
// Kernel 1: dynamic filters G[b] = tanh(W_w q + W_b) V_w^T -> ws; zero rowsum.
// ---------------------------------------------------------------------------
__global__ __launch_bounds__(512) void g_kernel(
    const float* __restrict__ query, const float* __restrict__ W_w,
    const float* __restrict__ W_b, const float* __restrict__ V_w,
    float* __restrict__ G_ws, float* __restrict__ rowsum)
{
    __shared__ float h_lds[AD];
    const int b    = blockIdx.x;
    const int tid  = threadIdx.x;
    const int w    = tid >> 6;
    const int lane = tid & 63;

    if (tid == 0) rowsum[b] = 0.f;   // main kernel atomicAdds into this

    const float4* q4 = (const float4*)(query + b * QD);
    float4 q0 = q4[lane];
    float4 q1 = q4[64 + lane];
    float4 q2 = q4[128 + lane];
    float4 q3 = q4[192 + lane];

    #pragma unroll 2
    for (int i = 0; i < 16; ++i) {
        int a = w * 16 + i;
        const float4* w4 = (const float4*)(W_w + a * QD);
        float4 x0 = w4[lane];
        float4 x1 = w4[64 + lane];
        float4 x2 = w4[128 + lane];
        float4 x3 = w4[192 + lane];
        float accA = 0.f, accB = 0.f;
        accA = fmaf(q0.x, x0.x, fmaf(q0.y, x0.y, fmaf(q0.z, x0.z, fmaf(q0.w, x0.w, accA))));
        accB = fmaf(q1.x, x1.x, fmaf(q1.y, x1.y, fmaf(q1.z, x1.z, fmaf(q1.w, x1.w, accB))));
        accA = fmaf(q2.x, x2.x, fmaf(q2.y, x2.y, fmaf(q2.z, x2.z, fmaf(q2.w, x2.w, accA))));
        accB = fmaf(q3.x, x3.x, fmaf(q3.y, x3.y, fmaf(q3.z, x3.z, fmaf(q3.w, x3.w, accB))));
        float acc = accA + accB;
        #pragma unroll
        for (int off = 32; off; off >>= 1) acc += __shfl_xor(acc, off);
        if (lane == 0) h_lds[a] = tanhf(acc + W_b[a]);
    }
    __syncthreads();

    for (int r = w; r < GN; r += 8) {
        float acc = fmaf(h_lds[lane], V_w[r * AD + lane],
                         h_lds[64 + lane] * V_w[r * AD + 64 + lane]);
        #pragma unroll
        for (int off = 32; off; off >>= 1) acc += __shfl_xor(acc, off);
        if (lane == 0) G_ws[b * GN + r] = acc;
    }
}

// ---------------------------------------------------------------------------
// Kernel 2 (main): grid = B*8, 256 threads. Block handles 256 t's of one b.
// Wave-local tiles exactly as R6 (verified layouts): conv-MFMA (im2col) ->
// wave-private LDS transpose -> swapped proj-MFMA (D row=a_loc, col=t) ->
// tanh via exp2/rcp with LDS-broadcast v-weights -> unnormalized s -> d_out;
// one atomicAdd(rowsum+b) per block. 2 barriers total.
// ---------------------------------------------------------------------------
__global__ __launch_bounds__(256, 5) void dca_main(
    const float* __restrict__ align, const float* __restrict__ P,
    const float* __restrict__ F_w, const float* __restrict__ U_w,
    const float* __restrict__ T_w, const float* __restrict__ T_b,
    const float* __restrict__ v_w, const float* __restrict__ G_ws,
    float* __restrict__ out, float* __restrict__ rowsum)
{
    __shared__ _Float16 al16[SEGT + 44];
    __shared__ float    pcb[SEGT];
    __shared__ _Float16 Xw[4 * 2 * 16 * XS2];   // 2 tiles per wave, 4 waves
    __shared__ float    vlds[AD];               // -2*v_w, epilogue broadcast
    __shared__ float    vsum_lds;
    __shared__ float    red[4];

    const int bid  = blockIdx.x;
    const int b    = bid >> 3;
    const int seg  = bid & (NSEG - 1);
    const int t0s  = seg * SEGT;
    const int tid  = threadIdx.x;
    const int lane = tid & 63;
    const int wid  = tid >> 6;
    const int l15  = lane & 15;
    const int quad = lane >> 4;

    // ---- stage segment of alignment row as f16 (local i ~ t = t0s + i-10) --
    for (int i = tid; i < SEGT + 44; i += 256) {
        int s = t0s + i - 10;
        float v = (s >= 0 && s < Tn) ? align[b * Tn + s] : 0.f;
        al16[i] = (_Float16)v;
    }
    // ---- v-weights to LDS (wave 0) + block-wide vsum ----
    if (tid < 32) {
        float4 v4 = ((const float4*)v_w)[tid];
        float s4 = v4.x + v4.y + v4.z + v4.w;
        #pragma unroll
        for (int off = 16; off; off >>= 1) s4 += __shfl_xor(s4, off);
        if (tid == 0) vsum_lds = s4;
        ((float4*)vlds)[tid] = make_float4(-2.f * v4.x, -2.f * v4.y,
                                           -2.f * v4.z, -2.f * v4.w);
    }
    __syncthreads();   // al16 + vlds + vsum ready

    // ---- prior for own-wave t's (write+read same wave: no barrier) ----
    {
        float pr = 0.f;
        #pragma unroll
        for (int k = 0; k < PLn; ++k) pr = fmaf((float)al16[tid + k], P[k], pr);
        pcb[tid] = fmaxf(pr, 1e-6f);
    }

    // ---- conv B-frag: B[k=quad*8+j][n=c=l15], taps>=21 zero ----
    f16x8 Bc = {};
    #pragma unroll
    for (int j = 0; j < 8; ++j) {
        int k = quad * 8 + j;
        float wv = 0.f;
        if (k < DKn) wv = (l15 < 8) ? F_w[l15 * DKn + k]
                                    : G_ws[b * GN + (l15 - 8) * DKn + k];
        Bc[j] = (_Float16)wv;
    }

    // ---- proj weight frags (MFMA A operand: A[m=a_loc=l15][k]) ----
    // k=0..7: U, k=8..15: T, k=16: bias channel (x TWO_LOG2E fold).
    f16x8 Bf[8];
    #pragma unroll
    for (int n = 0; n < 8; ++n) {
        int a = n * 16 + l15;
        f16x8 bf = {};
        if (quad < 2) {
            const float* src = (quad == 0) ? (U_w + a * 8) : (T_w + a * 8);
            float4 lo = ((const float4*)src)[0];
            float4 hi = ((const float4*)src)[1];
            bf[0] = (_Float16)(TWO_LOG2E * lo.x); bf[1] = (_Float16)(TWO_LOG2E * lo.y);
            bf[2] = (_Float16)(TWO_LOG2E * lo.z); bf[3] = (_Float16)(TWO_LOG2E * lo.w);
            bf[4] = (_Float16)(TWO_LOG2E * hi.x); bf[5] = (_Float16)(TWO_LOG2E * hi.y);
            bf[6] = (_Float16)(TWO_LOG2E * hi.z); bf[7] = (_Float16)(TWO_LOG2E * hi.w);
        } else if (quad == 2) {
            bf[0] = (_Float16)(TWO_LOG2E * T_b[a]);
        }
        Bf[n] = bf;
    }
    const float vsum = vsum_lds;

    // ---- main loop: wave owns 64 t's = 4 tiles, as 2 iters x 2 tiles ----
    const int tw = wid * 64;            // wave's local t base
    _Float16* Xp0 = &Xw[wid * 2 * 16 * XS2];
    _Float16* Xp1 = Xp0 + 16 * XS2;
    float* orow = out + b * Tn + t0s;
    float wsum = 0.f;

    #pragma unroll 1
    for (int m = 0; m < 2; ++m) {
        const int tlA = tw + m * 32;
        const int tlB = tlA + 16;

        f16x8 Ac0, Ac1;
        #pragma unroll
        for (int j = 0; j < 8; ++j) {
            Ac0[j] = al16[tlA + l15 + quad * 8 + j];
            Ac1[j] = al16[tlB + l15 + quad * 8 + j];
        }
        f32x4 z = {};
        f32x4 X0 = __builtin_amdgcn_mfma_f32_16x16x32_f16(Ac0, Bc, z, 0, 0, 0);
        f32x4 X1 = __builtin_amdgcn_mfma_f32_16x16x32_f16(Ac1, Bc, z, 0, 0, 0);

        #pragma unroll
        for (int r = 0; r < 4; ++r) {
            Xp0[(quad * 4 + r) * XS2 + l15] = (_Float16)X0[r];
            Xp1[(quad * 4 + r) * XS2 + l15] = (_Float16)X1[r];
        }
        __asm__ __volatile__("" ::: "memory");  // keep order; DS in-order/wave

        f16x8 B20 = {}, B21 = {};
        if (quad < 2) {
            B20 = *(const f16x8*)&Xp0[l15 * XS2 + quad * 8];
            B21 = *(const f16x8*)&Xp1[l15 * XS2 + quad * 8];
        } else if (quad == 2) {
            B20[0] = (_Float16)1.f;   // bias channel k=16
            B21[0] = (_Float16)1.f;
        }

        float es0 = 0.f, es1 = 0.f;
        #pragma unroll
        for (int n = 0; n < 8; ++n) {
            f32x4 vq = *(const f32x4*)&vlds[n * 16 + quad * 4];  // broadcast
            f32x4 z2 = {};
            f32x4 d0 = __builtin_amdgcn_mfma_f32_16x16x32_f16(Bf[n], B20, z2, 0, 0, 0);
            f32x4 d1 = __builtin_amdgcn_mfma_f32_16x16x32_f16(Bf[n], B21, z2, 0, 0, 0);
            #pragma unroll
            for (int r = 0; r < 4; ++r) {
                float qa = __builtin_amdgcn_exp2f(d0[r]);
                float qb = __builtin_amdgcn_exp2f(d1[r]);
                float ra = __builtin_amdgcn_rcpf(qa + 1.f);
                float rb = __builtin_amdgcn_rcpf(qb + 1.f);
                es0 = fmaf(vq[r], ra, es0);
                es1 = fmaf(vq[r], rb, es1);
            }
        }
        es0 += __shfl_xor(es0, 16);
        es0 += __shfl_xor(es0, 32);
        es1 += __shfl_xor(es1, 16);
        es1 += __shfl_xor(es1, 32);

        if (lane < 16) {
            float svA = pcb[tlA + lane] * __expf(es0 + vsum);
            float svB = pcb[tlB + lane] * __expf(es1 + vsum);
            orow[tlA + lane] = svA;
            orow[tlB + lane] = svB;
            wsum += svA + svB;
        }
    }

    // ---- block partial sum -> one atomic ----
    #pragma unroll
    for (int off = 32; off; off >>= 1) wsum += __shfl_xor(wsum, off);
    if (lane == 0) red[wid] = wsum;
    __syncthreads();
    if (tid == 0)
        atomicAdd(rowsum + b, red[0] + red[1] + red[2] + red[3]);
}

// ---------------------------------------------------------------------------
// Kernel 3: in-place row normalization.
// ---------------------------------------------------------------------------
__global__ __launch_bounds__(256) void norm_kernel(
    float* __restrict__ out, const float* __restrict__ rowsum)
{
    const int b = blockIdx.x;
    const float inv = 1.f / rowsum[b];
    float4* o = (float4*)(out + b * Tn);
    #pragma unroll
    for (int i = 0; i < Tn / 4 / 256; ++i) {
        int idx = i * 256 + threadIdx.x;
        float4 v = o[idx];
        v.x *= inv; v.y *= inv; v.z *= inv; v.w *= inv;
        o[idx] = v;
    }
}

// ---------------------------------------------------------------------------
extern "C" void kernel_launch(void* const* d_in, const int* in_sizes, int n_in,
                              void* d_out, int out_size, void* d_ws, size_t ws_size,
                              hipStream_t stream) {
    const float* query = (const float*)d_in[0];
    const float* align = (const float*)d_in[1];
    const float* P     = (const float*)d_in[2];
    const float* W_w   = (const float*)d_in[3];
    const float* W_b   = (const float*)d_in[4];
    const float* V_w   = (const float*)d_in[5];
    const float* F_w   = (const float*)d_in[6];
    const float* U_w   = (const float*)d_in[7];
    const float* T_w   = (const float*)d_in[8];
    const float* T_b   = (const float*)d_in[9];
    const float* v_w   = (const float*)d_in[10];
    float* out    = (float*)d_out;
    float* G_ws   = (float*)d_ws;            // 256*168 floats
    float* rowsum = G_ws + Bsz * GN;         // 256 floats

    g_kernel<<<Bsz, 512, 0, stream>>>(query, W_w, W_b, V_w, G_ws, rowsum);
    dca_main<<<Bsz * NSEG, 256, 0, stream>>>(align, P, F_w, U_w, T_w, T_b,
                                             v_w, G_ws, out, rowsum);
    norm_kernel<<<Bsz, 256, 0, stream>>>(out, rowsum);
}